// Round 2
// baseline (224.438 us; speedup 1.0000x reference)
//
#include <hip/hip_runtime.h>
#include <stdint.h>
#include <stddef.h>

#define DIM 1024
#define EPS 1e-8f

typedef __attribute__((ext_vector_type(4)))  int   i32x4;
typedef __attribute__((ext_vector_type(8)))  int   i32x8;
typedef __attribute__((ext_vector_type(16))) float f32x16;

// e8m0 scale byte 123 = 2^(123-127) = 1/16 per operand -> 1/256 on the product,
// exactly cancelling the x16 prep scaling (bit-exact pow2 exponent shift).
#define SCALE8 0x7B7B7B7B

// async global->LDS, 16B per lane, wave-uniform LDS base + lane*16
__device__ __forceinline__ void async_copy16(const void* g, void* l) {
    __builtin_amdgcn_global_load_lds(
        (__attribute__((address_space(1))) void*)const_cast<void*>(g),
        (__attribute__((address_space(3))) void*)(l), 16, 0, 0);
}

// drain all but newest N vmem ops, then barrier
#define PIPE_SYNC(N) asm volatile("s_waitcnt vmcnt(" #N ")\n\ts_barrier" ::: "memory")

// ---------------------------------------------------------------------------
// Prep: wave-per-row. Unit-normalize, scale by 16 (undone by hw e8m0 scales in
// the GEMM), cast to OCP fp8 e4m3, store rows LINEARLY (k ascending) with
// coalesced dword stores. The GEMM's staging-side chunk XOR supplies the LDS
// bank swizzle.
// ---------------------------------------------------------------------------
__global__ __launch_bounds__(256)
void prep_all(const float* __restrict__ x, const float* __restrict__ pos,
              const float* __restrict__ neg,
              unsigned char* __restrict__ Xn, unsigned char* __restrict__ Nn,
              float* __restrict__ simOut, float* __restrict__ rowsum, int bn) {
    const int lane = threadIdx.x & 63;
    const int wave = threadIdx.x >> 6;
    const int grow = blockIdx.x * 4 + wave;
    const bool isX = grow < bn;
    const int row  = isX ? grow : grow - bn;
    const float* src = isX ? x : neg;
    unsigned char* dst = isX ? Xn : Nn;

    const float4* s = (const float4*)(src + (size_t)row * DIM);
    float4 xv[4], pv[4];
    float sxx = 0.f, spp = 0.f, sxp = 0.f;
#pragma unroll
    for (int i = 0; i < 4; i++) {
        xv[i] = s[lane + 64 * i];
        sxx += xv[i].x * xv[i].x + xv[i].y * xv[i].y + xv[i].z * xv[i].z + xv[i].w * xv[i].w;
    }
    if (isX) {
        const float4* p = (const float4*)(pos + (size_t)row * DIM);
#pragma unroll
        for (int i = 0; i < 4; i++) {
            pv[i] = p[lane + 64 * i];
            spp += pv[i].x * pv[i].x + pv[i].y * pv[i].y + pv[i].z * pv[i].z + pv[i].w * pv[i].w;
            sxp += xv[i].x * pv[i].x + xv[i].y * pv[i].y + xv[i].z * pv[i].z + xv[i].w * pv[i].w;
        }
#pragma unroll
        for (int off = 1; off < 64; off <<= 1) {
            sxx += __shfl_xor(sxx, off);
            spp += __shfl_xor(spp, off);
            sxp += __shfl_xor(sxp, off);
        }
    } else {
#pragma unroll
        for (int off = 1; off < 64; off <<= 1) sxx += __shfl_xor(sxx, off);
    }
    const float nx  = sqrtf(sxx);
    const float inv = (nx > 0.f) ? (16.f / nx) : 0.f;   // x16 -> e4m3 sweet spot
    if (isX && lane == 0) {
        const float np = sqrtf(spp);
        simOut[row] = sxp / fmaxf(nx * np, EPS);
        rowsum[row] = 0.f;
    }
    unsigned int t;
    t = __builtin_amdgcn_cvt_pk_fp8_f32(xv[0].x * inv, xv[0].y * inv, 0, false);
    unsigned int q0 = __builtin_amdgcn_cvt_pk_fp8_f32(xv[0].z * inv, xv[0].w * inv, t, true);
    t = __builtin_amdgcn_cvt_pk_fp8_f32(xv[1].x * inv, xv[1].y * inv, 0, false);
    unsigned int q1 = __builtin_amdgcn_cvt_pk_fp8_f32(xv[1].z * inv, xv[1].w * inv, t, true);
    t = __builtin_amdgcn_cvt_pk_fp8_f32(xv[2].x * inv, xv[2].y * inv, 0, false);
    unsigned int q2 = __builtin_amdgcn_cvt_pk_fp8_f32(xv[2].z * inv, xv[2].w * inv, t, true);
    t = __builtin_amdgcn_cvt_pk_fp8_f32(xv[3].x * inv, xv[3].y * inv, 0, false);
    unsigned int q3 = __builtin_amdgcn_cvt_pk_fp8_f32(xv[3].z * inv, xv[3].w * inv, t, true);

    unsigned int* wr = (unsigned int*)(dst + (size_t)row * DIM);
    wr[lane]       = q0;
    wr[lane + 64]  = q1;
    wr[lane + 128] = q2;
    wr[lane + 192] = q3;
}

// ---------------------------------------------------------------------------
// Fused MX-fp8 GEMM: rowsum[i] += sum_j exp( unit(x_i) . unit(neg_j) )
// 256x256 tile, 8 waves (512 thr), per-wave output 128x64 (4x2 frags of
// 32x32x64). BK=64-B k-window per stage, FOUR-buffer rotation in 128 KB
// dynamic LDS, prefetch distance 3 via s_waitcnt vmcnt(8)+s_barrier.
// Per phase per wave: 12 ds_read_b128 + 8 mfma_scale_f32_32x32x64_f8f6f4
// (2x the per-phase MFMA of the 128^2 version -> amortizes barrier/wait
// overhead that capped MfmaUtil at 10.7%).
// Protocol identical to the verified 128^2 kernel: per wave 4 glds per STAGE,
// waitcnt-then-barrier; reads of phase s-1 are consumed (lgkm-waited) by
// MFMAs before barrier arrival, so STAGE overwrite after the barrier is safe.
// Bank pattern per 16-lane group tiles all 32 banks 2x (free) — same
// row-XOR chunk swizzle on both staging and read sides.
// ---------------------------------------------------------------------------
__global__ __launch_bounds__(512, 2)
void gemm_exp_rowsum(const unsigned char* __restrict__ Xn,
                     const unsigned char* __restrict__ Nn,
                     float* __restrict__ rowsum) {
    constexpr int KB   = DIM;        // 1024 bytes per fp8 row
    constexpr int BK   = 64;         // bytes per stage-row (one k-window)
    constexpr int TILE = 256;
    constexpr int BUFB = TILE * BK;  // 16 KB per buffer per matrix
    extern __shared__ unsigned char smem[];          // 4*BUFB (A) | 4*BUFB (B)
    unsigned char* Ash = smem;
    unsigned char* Bsh = smem + 4 * BUFB;

    const int tid  = threadIdx.x;
    const int lane = tid & 63;
    const int wave = tid >> 6;                        // 0..7
    const int rowBase = blockIdx.y * TILE;
    const int colBase = blockIdx.x * TILE;

    // staging: one glds = 1 KB = 16 rows x 64 B; lane -> (row, chunk).
    // LDS chunk slot p of row r receives global logical chunk p ^ ((r>>1)&3).
    const int srow   = lane >> 2;                       // 0..15
    const int schunk = (lane & 3) ^ ((srow >> 1) & 3);  // global-side swizzle
    const unsigned char* gA = Xn + (size_t)(rowBase + wave * 16 + srow) * KB + schunk * 16;
    const unsigned char* gB = Nn + (size_t)(colBase + wave * 16 + srow) * KB + schunk * 16;
    const int l0 = (wave * 16) * BK;                    // rows wave*16 ..
    const int l1 = (wave * 16 + 128) * BK;              // rows 128+wave*16 ..

    f32x16 acc[4][2];
#pragma unroll
    for (int mi = 0; mi < 4; mi++)
#pragma unroll
        for (int ni = 0; ni < 2; ni++)
#pragma unroll
            for (int e = 0; e < 16; e++) acc[mi][ni][e] = 0.f;

    const int m0   = (wave >> 2) * 128;  // M-half
    const int n0   = (wave & 3) * 64;    // N-quarter
    const int mrow = lane & 31;          // row within a 32-row fragment
    const int kh   = lane >> 5;          // k-half (bytes 32*kh..+32 of window)
    const int kx   = (mrow >> 1) & 3;    // read-side swizzle key
    const int c0   = ((2 * kh) ^ kx) << 4;   // slot of logical chunk 2kh
    // slot of logical chunk 2kh+1 is c0 ^ 16

    int arow[4], brow[2];
#pragma unroll
    for (int i = 0; i < 4; i++) arow[i] = (m0 + 32 * i + mrow) * BK;
#pragma unroll
    for (int i = 0; i < 2; i++) brow[i] = (n0 + 32 * i + mrow) * BK;

#define STAGE(buf, stg)                                                   \
    do {                                                                  \
        const int kq = (stg) * BK;                                        \
        async_copy16(gA + kq,            Ash + (buf) * BUFB + l0);        \
        async_copy16(gA + 128 * KB + kq, Ash + (buf) * BUFB + l1);        \
        async_copy16(gB + kq,            Bsh + (buf) * BUFB + l0);        \
        async_copy16(gB + 128 * KB + kq, Bsh + (buf) * BUFB + l1);        \
    } while (0)

#define COMPUTE(buf)                                                      \
    do {                                                                  \
        const unsigned char* Ab = Ash + (buf) * BUFB;                     \
        const unsigned char* Bb = Bsh + (buf) * BUFB;                     \
        i32x8 Bf[2];                                                      \
        _Pragma("unroll")                                                 \
        for (int ni = 0; ni < 2; ni++) {                                  \
            i32x4 lo = *(const i32x4*)(Bb + brow[ni] + c0);               \
            i32x4 hi = *(const i32x4*)(Bb + brow[ni] + (c0 ^ 16));        \
            Bf[ni] = __builtin_shufflevector(lo, hi, 0, 1, 2, 3, 4, 5, 6, 7); \
        }                                                                 \
        _Pragma("unroll")                                                 \
        for (int mi = 0; mi < 4; mi++) {                                  \
            i32x4 lo = *(const i32x4*)(Ab + arow[mi] + c0);               \
            i32x4 hi = *(const i32x4*)(Ab + arow[mi] + (c0 ^ 16));        \
            i32x8 Af = __builtin_shufflevector(lo, hi, 0, 1, 2, 3, 4, 5, 6, 7); \
            acc[mi][0] = __builtin_amdgcn_mfma_scale_f32_32x32x64_f8f6f4( \
                Af, Bf[0], acc[mi][0], 0, 0, 0, SCALE8, 0, SCALE8);       \
            acc[mi][1] = __builtin_amdgcn_mfma_scale_f32_32x32x64_f8f6f4( \
                Af, Bf[1], acc[mi][1], 0, 0, 0, SCALE8, 0, SCALE8);       \
        }                                                                 \
    } while (0)

    STAGE(0, 0);
    STAGE(1, 1);
    STAGE(2, 2);
    // 16 stages; stage s computed at phase s in buffer s%4, staged 3 ahead.
    // vmcnt(8): 12 in flight (s+1,s+2,s+3); wait drains stage s's 4 ops.
#pragma unroll
    for (int s = 0; s < 13; s++) {
        PIPE_SYNC(8);
        STAGE((s + 3) & 3, s + 3);
        COMPUTE(s & 3);
    }
    PIPE_SYNC(8); COMPUTE(1);   // stage 13 (14,15 remain in flight)
    PIPE_SYNC(4); COMPUTE(2);   // stage 14
    PIPE_SYNC(0); COMPUTE(3);   // stage 15
#undef STAGE
#undef COMPUTE

    // epilogue: acc holds unit-vector dots (hw e8m0 scales applied).
    // 32x32 C/D layout: col = lane&31, row = (reg&3) + 8*(reg>>2) + 4*kh.
    // exp, sum the two ni-column-blocks, reduce the 32 cols per half-wave,
    // one atomic per row per block.
#pragma unroll
    for (int mi = 0; mi < 4; mi++) {
        float rs[16];
#pragma unroll
        for (int r = 0; r < 16; r++) {
            float v = __expf(acc[mi][0][r]) + __expf(acc[mi][1][r]);
            v += __shfl_xor(v, 1);
            v += __shfl_xor(v, 2);
            v += __shfl_xor(v, 4);
            v += __shfl_xor(v, 8);
            v += __shfl_xor(v, 16);
            rs[r] = v;
        }
        if ((lane & 31) == 0) {
            const int rbase = rowBase + m0 + 32 * mi + 4 * kh;
#pragma unroll
            for (int r = 0; r < 16; r++)
                atomicAdd(&rowsum[rbase + (r & 3) + 8 * (r >> 2)], rs[r]);
        }
    }
}

__global__ __launch_bounds__(1024)
void loss_kernel(const float* __restrict__ rowsum, const float* __restrict__ sim,
                 float* __restrict__ out, int bn) {
    const int tid  = threadIdx.x;
    const int lane = tid & 63;
    const int wave = tid >> 6;
    float acc = 0.f;
    for (int i = tid; i < bn; i += 1024) acc += logf(rowsum[i]) - sim[i];
#pragma unroll
    for (int off = 1; off < 64; off <<= 1) acc += __shfl_xor(acc, off);
    __shared__ float red[16];
    if (lane == 0) red[wave] = acc;
    __syncthreads();
    if (tid == 0) {
        float t = 0.f;
#pragma unroll
        for (int i = 0; i < 16; i++) t += red[i];
        out[0] = t / (float)bn;
    }
}

extern "C" void kernel_launch(void* const* d_in, const int* in_sizes, int n_in,
                              void* d_out, int out_size, void* d_ws, size_t ws_size,
                              hipStream_t stream) {
    const float* x   = (const float*)d_in[0];
    const float* pos = (const float*)d_in[1];
    const float* neg = (const float*)d_in[2];
    const int bn = in_sizes[0] / DIM;  // 4096
    const int cn = in_sizes[2] / DIM;  // 8192

    // ws layout: Xn fp8 [bn*DIM] | Nn fp8 [cn*DIM] | sim f32 [bn] | rowsum f32 [bn]
    unsigned char* Xn = (unsigned char*)d_ws;
    unsigned char* Nn = Xn + (size_t)bn * DIM;
    float* sim    = (float*)(Nn + (size_t)cn * DIM);
    float* rowsum = sim + bn;

    // opt in to 128 KB dynamic LDS (gfx950 has 160 KB/CU); harmless if
    // already allowed. Host-side attribute set — not a stream op, graph-safe.
    static bool attr_done = false;
    if (!attr_done) {
        (void)hipFuncSetAttribute((const void*)gemm_exp_rowsum,
                                  hipFuncAttributeMaxDynamicSharedMemorySize,
                                  131072);
        attr_done = true;
    }

    prep_all<<<dim3((bn + cn) / 4), dim3(256), 0, stream>>>(x, pos, neg, Xn, Nn, sim, rowsum, bn);
    gemm_exp_rowsum<<<dim3(cn / 256, bn / 256), dim3(512), 131072, stream>>>(Xn, Nn, rowsum);
    loss_kernel<<<dim3(1), dim3(1024), 0, stream>>>(rowsum, sim, (float*)d_out, bn);
}

// Round 3
// 169.216 us; speedup vs baseline: 1.3263x; 1.3263x over previous
//
#include <hip/hip_runtime.h>
#include <stdint.h>
#include <stddef.h>

#define DIM 1024
#define EPS 1e-8f

typedef __attribute__((ext_vector_type(4)))  int   i32x4;
typedef __attribute__((ext_vector_type(8)))  int   i32x8;
typedef __attribute__((ext_vector_type(4)))  float f32x4;

// e8m0 scale byte 123 = 2^(123-127) = 1/16 per operand -> 1/256 on the product,
// exactly cancelling the x16 prep scaling (bit-exact pow2 exponent shift).
// All 4 bytes equal -> opsel-proof.
#define SCALE8 0x7B7B7B7B

// async global->LDS, 16B per lane, wave-uniform LDS base + lane*16
__device__ __forceinline__ void async_copy16(const void* g, void* l) {
    __builtin_amdgcn_global_load_lds(
        (__attribute__((address_space(1))) void*)const_cast<void*>(g),
        (__attribute__((address_space(3))) void*)(l), 16, 0, 0);
}

// ---------------------------------------------------------------------------
// Prep: wave-per-row. Unit-normalize, scale by 16 (undone by hw e8m0 scales in
// the GEMM), cast to OCP fp8 e4m3, store rows LINEARLY (k ascending) with
// coalesced dword stores. The GEMM's staging-side chunk XOR supplies the LDS
// bank swizzle.
// ---------------------------------------------------------------------------
__global__ __launch_bounds__(256)
void prep_all(const float* __restrict__ x, const float* __restrict__ pos,
              const float* __restrict__ neg,
              unsigned char* __restrict__ Xn, unsigned char* __restrict__ Nn,
              float* __restrict__ simOut, float* __restrict__ rowsum, int bn) {
    const int lane = threadIdx.x & 63;
    const int wave = threadIdx.x >> 6;
    const int grow = blockIdx.x * 4 + wave;
    const bool isX = grow < bn;
    const int row  = isX ? grow : grow - bn;
    const float* src = isX ? x : neg;
    unsigned char* dst = isX ? Xn : Nn;

    const float4* s = (const float4*)(src + (size_t)row * DIM);
    float4 xv[4], pv[4];
    float sxx = 0.f, spp = 0.f, sxp = 0.f;
#pragma unroll
    for (int i = 0; i < 4; i++) {
        xv[i] = s[lane + 64 * i];
        sxx += xv[i].x * xv[i].x + xv[i].y * xv[i].y + xv[i].z * xv[i].z + xv[i].w * xv[i].w;
    }
    if (isX) {
        const float4* p = (const float4*)(pos + (size_t)row * DIM);
#pragma unroll
        for (int i = 0; i < 4; i++) {
            pv[i] = p[lane + 64 * i];
            spp += pv[i].x * pv[i].x + pv[i].y * pv[i].y + pv[i].z * pv[i].z + pv[i].w * pv[i].w;
            sxp += xv[i].x * pv[i].x + xv[i].y * pv[i].y + xv[i].z * pv[i].z + xv[i].w * pv[i].w;
        }
#pragma unroll
        for (int off = 1; off < 64; off <<= 1) {
            sxx += __shfl_xor(sxx, off);
            spp += __shfl_xor(spp, off);
            sxp += __shfl_xor(sxp, off);
        }
    } else {
#pragma unroll
        for (int off = 1; off < 64; off <<= 1) sxx += __shfl_xor(sxx, off);
    }
    const float nx  = sqrtf(sxx);
    const float inv = (nx > 0.f) ? (16.f / nx) : 0.f;   // x16 -> e4m3 sweet spot
    if (isX && lane == 0) {
        const float np = sqrtf(spp);
        simOut[row] = sxp / fmaxf(nx * np, EPS);
        rowsum[row] = 0.f;
    }
    unsigned int t;
    t = __builtin_amdgcn_cvt_pk_fp8_f32(xv[0].x * inv, xv[0].y * inv, 0, false);
    unsigned int q0 = __builtin_amdgcn_cvt_pk_fp8_f32(xv[0].z * inv, xv[0].w * inv, t, true);
    t = __builtin_amdgcn_cvt_pk_fp8_f32(xv[1].x * inv, xv[1].y * inv, 0, false);
    unsigned int q1 = __builtin_amdgcn_cvt_pk_fp8_f32(xv[1].z * inv, xv[1].w * inv, t, true);
    t = __builtin_amdgcn_cvt_pk_fp8_f32(xv[2].x * inv, xv[2].y * inv, 0, false);
    unsigned int q2 = __builtin_amdgcn_cvt_pk_fp8_f32(xv[2].z * inv, xv[2].w * inv, t, true);
    t = __builtin_amdgcn_cvt_pk_fp8_f32(xv[3].x * inv, xv[3].y * inv, 0, false);
    unsigned int q3 = __builtin_amdgcn_cvt_pk_fp8_f32(xv[3].z * inv, xv[3].w * inv, t, true);

    unsigned int* wr = (unsigned int*)(dst + (size_t)row * DIM);
    wr[lane]       = q0;
    wr[lane + 64]  = q1;
    wr[lane + 128] = q2;
    wr[lane + 192] = q3;
}

// ---------------------------------------------------------------------------
// Fused MX-fp8 GEMM: rowsum[i] += sum_j exp( unit(x_i) . unit(neg_j) )
// m148-proven cell: mfma_scale_f32_16x16x128_f8f6f4 (4-reg C/D) in the m97
// single-buffer 2-barrier structure. 128x128 tile, 4 waves, BK=128-B
// k-window (K=1024 -> 8 windows), 32 KB LDS, 3 blocks/CU for cross-block
// desync (hides the vmcnt(0) drain, m114 mechanism).
// Per window per wave: 16 ds_read_b128 + 16 mfma_scale.
// LDS swizzle: 128-B row = 8 chunks of 16 B; physical slot = logical ^ (row&7)
// -> each 16-lane read group tiles all 32 banks 2x (free). Staging applies the
// same permutation on the GLOBAL side (glds dst stays linear, m104/m173 rule).
// Fragment (R1-validated family): lane&15 = row, q=lane>>4 holds contiguous
// k-bytes [32q, 32q+32) as 2 b128 at slots (2q)^(r&7) and that ^1.
// HW e8m0 scales (0x7B each side) undo the x16*x16 prep scaling.
// ---------------------------------------------------------------------------
__global__ __launch_bounds__(256, 3)
void gemm_exp_rowsum(const unsigned char* __restrict__ Xn,
                     const unsigned char* __restrict__ Nn,
                     float* __restrict__ rowsum) {
    constexpr int KB = DIM;          // 1024 bytes per fp8 row
    constexpr int BK = 128;          // bytes per k-window (K=128 elems)
    __shared__ __align__(16) unsigned char Ash[128 * BK];   // 16 KB
    __shared__ __align__(16) unsigned char Bsh[128 * BK];   // 16 KB

    const int tid  = threadIdx.x;
    const int lane = tid & 63;
    const int wave = tid >> 6;                 // 0..3
    const int rowBase = blockIdx.y * 128;
    const int colBase = blockIdx.x * 128;

    // staging: one glds = 1 KB = 8 rows x 128 B. lane -> (row=lane>>3, slot=lane&7).
    // physical slot p of row r holds logical chunk p ^ (r&7)  (r%8 == lane>>3 here).
    const int srow = lane >> 3;                         // 0..7
    const int sch  = (lane & 7) ^ srow;                 // global-side swizzle
    const int w32  = wave * 32;                         // this wave stages rows [w32, w32+32)
    const unsigned char* gA = Xn + (size_t)(rowBase + w32 + srow) * KB + sch * 16;
    const unsigned char* gB = Nn + (size_t)(colBase + w32 + srow) * KB + sch * 16;

    const f32x4 fz = {0.f, 0.f, 0.f, 0.f};
    f32x4 acc[4][4];
#pragma unroll
    for (int mi = 0; mi < 4; mi++)
#pragma unroll
        for (int ni = 0; ni < 4; ni++) acc[mi][ni] = fz;

    const int m0   = (wave >> 1) * 64;
    const int n0   = (wave & 1) * 64;
    const int mrow = lane & 15;          // fragment row
    const int q    = lane >> 4;          // k-quarter: bytes [32q, 32q+32)
    const int c0   = ((2 * q) ^ (mrow & 7)) << 4;   // slot byte-off of 1st 16B (2nd = ^16)

    int aoff[4], boff[4];
#pragma unroll
    for (int i = 0; i < 4; i++) {
        aoff[i] = (m0 + 16 * i + mrow) * BK + c0;
        boff[i] = (n0 + 16 * i + mrow) * BK + c0;
    }

#define STAGE(stg)                                                        \
    do {                                                                  \
        const int kq = (stg) * BK;                                        \
        _Pragma("unroll")                                                 \
        for (int i = 0; i < 4; i++) {                                     \
            async_copy16(gA + (size_t)(8 * i) * KB + kq, Ash + (w32 + 8 * i) * BK); \
            async_copy16(gB + (size_t)(8 * i) * KB + kq, Bsh + (w32 + 8 * i) * BK); \
        }                                                                 \
    } while (0)

#define COMPUTE()                                                         \
    do {                                                                  \
        i32x8 Af[4], Bf[4];                                               \
        _Pragma("unroll")                                                 \
        for (int i = 0; i < 4; i++) {                                     \
            i32x4 alo = *(const i32x4*)(Ash + aoff[i]);                   \
            i32x4 ahi = *(const i32x4*)(Ash + (aoff[i] ^ 16));            \
            Af[i] = __builtin_shufflevector(alo, ahi, 0, 1, 2, 3, 4, 5, 6, 7); \
            i32x4 blo = *(const i32x4*)(Bsh + boff[i]);                   \
            i32x4 bhi = *(const i32x4*)(Bsh + (boff[i] ^ 16));            \
            Bf[i] = __builtin_shufflevector(blo, bhi, 0, 1, 2, 3, 4, 5, 6, 7); \
        }                                                                 \
        _Pragma("unroll")                                                 \
        for (int mi = 0; mi < 4; mi++)                                    \
            _Pragma("unroll")                                             \
            for (int ni = 0; ni < 4; ni++)                                \
                acc[mi][ni] = __builtin_amdgcn_mfma_scale_f32_16x16x128_f8f6f4( \
                    Af[mi], Bf[ni], acc[mi][ni], 0, 0, 0, SCALE8, 0, SCALE8); \
    } while (0)

    // m97 2-barrier loop: STAGE k; drain+barrier; COMPUTE k; barrier.
    // Drain stall is hidden by 3-block/CU desync (blocks at different phases).
#pragma unroll
    for (int s = 0; s < 8; s++) {
        STAGE(s);
        asm volatile("s_waitcnt vmcnt(0)\n\ts_barrier" ::: "memory");
        COMPUTE();
        __syncthreads();
    }
#undef STAGE
#undef COMPUTE

    // epilogue: acc holds unit-vector dots (hw e8m0 scales applied).
    // 16x16 C/D layout: col = lane&15, row = q*4 + reg.
    // exp, sum the 4 ni column-blocks, reduce 16 cols, 4 atomics per q-lane.
#pragma unroll
    for (int mi = 0; mi < 4; mi++) {
        float rs0 = 0.f, rs1 = 0.f, rs2 = 0.f, rs3 = 0.f;
#pragma unroll
        for (int ni = 0; ni < 4; ni++) {
            rs0 += __expf(acc[mi][ni].x);
            rs1 += __expf(acc[mi][ni].y);
            rs2 += __expf(acc[mi][ni].z);
            rs3 += __expf(acc[mi][ni].w);
        }
#pragma unroll
        for (int off = 1; off < 16; off <<= 1) {
            rs0 += __shfl_xor(rs0, off);
            rs1 += __shfl_xor(rs1, off);
            rs2 += __shfl_xor(rs2, off);
            rs3 += __shfl_xor(rs3, off);
        }
        if ((lane & 15) == 0) {
            const int r = rowBase + m0 + mi * 16 + q * 4;
            atomicAdd(&rowsum[r + 0], rs0);
            atomicAdd(&rowsum[r + 1], rs1);
            atomicAdd(&rowsum[r + 2], rs2);
            atomicAdd(&rowsum[r + 3], rs3);
        }
    }
}

__global__ __launch_bounds__(1024)
void loss_kernel(const float* __restrict__ rowsum, const float* __restrict__ sim,
                 float* __restrict__ out, int bn) {
    const int tid  = threadIdx.x;
    const int lane = tid & 63;
    const int wave = tid >> 6;
    float acc = 0.f;
    for (int i = tid; i < bn; i += 1024) acc += logf(rowsum[i]) - sim[i];
#pragma unroll
    for (int off = 1; off < 64; off <<= 1) acc += __shfl_xor(acc, off);
    __shared__ float red[16];
    if (lane == 0) red[wave] = acc;
    __syncthreads();
    if (tid == 0) {
        float t = 0.f;
#pragma unroll
        for (int i = 0; i < 16; i++) t += red[i];
        out[0] = t / (float)bn;
    }
}

extern "C" void kernel_launch(void* const* d_in, const int* in_sizes, int n_in,
                              void* d_out, int out_size, void* d_ws, size_t ws_size,
                              hipStream_t stream) {
    const float* x   = (const float*)d_in[0];
    const float* pos = (const float*)d_in[1];
    const float* neg = (const float*)d_in[2];
    const int bn = in_sizes[0] / DIM;  // 4096
    const int cn = in_sizes[2] / DIM;  // 8192

    // ws layout: Xn fp8 [bn*DIM] | Nn fp8 [cn*DIM] | sim f32 [bn] | rowsum f32 [bn]
    unsigned char* Xn = (unsigned char*)d_ws;
    unsigned char* Nn = Xn + (size_t)bn * DIM;
    float* sim    = (float*)(Nn + (size_t)cn * DIM);
    float* rowsum = sim + bn;

    prep_all<<<dim3((bn + cn) / 4), dim3(256), 0, stream>>>(x, pos, neg, Xn, Nn, sim, rowsum, bn);
    gemm_exp_rowsum<<<dim3(cn / 128, bn / 128), dim3(256), 0, stream>>>(Xn, Nn, rowsum);
    loss_kernel<<<dim3(1), dim3(1024), 0, stream>>>(rowsum, sim, (float*)d_out, bn);
}

// Round 4
// 157.019 us; speedup vs baseline: 1.4294x; 1.0777x over previous
//
#include <hip/hip_runtime.h>
#include <stdint.h>
#include <stddef.h>

#define DIM 1024
#define EPS 1e-8f

typedef __attribute__((ext_vector_type(4)))  int   i32x4;
typedef __attribute__((ext_vector_type(8)))  int   i32x8;
typedef __attribute__((ext_vector_type(4)))  float f32x4;

// e8m0 scale byte 123 = 2^(123-127) = 1/16 per operand -> 1/256 on the product,
// exactly cancelling the x16 prep scaling (bit-exact pow2 exponent shift).
#define SCALE8 0x7B7B7B7B

// async global->LDS, 16B per lane, wave-uniform LDS base + lane*16
__device__ __forceinline__ void async_copy16(const void* g, void* l) {
    __builtin_amdgcn_global_load_lds(
        (__attribute__((address_space(1))) void*)const_cast<void*>(g),
        (__attribute__((address_space(3))) void*)(l), 16, 0, 0);
}

// ---------------------------------------------------------------------------
// Prep: wave-per-row. Unit-normalize, scale by 16 (undone by hw e8m0 scales in
// the GEMM), cast to OCP fp8 e4m3, store rows LINEARLY with coalesced dword
// stores. The GEMM's staging-side chunk XOR supplies the LDS bank swizzle.
// ---------------------------------------------------------------------------
__global__ __launch_bounds__(256)
void prep_all(const float* __restrict__ x, const float* __restrict__ pos,
              const float* __restrict__ neg,
              unsigned char* __restrict__ Xn, unsigned char* __restrict__ Nn,
              float* __restrict__ simOut, float* __restrict__ rowsum, int bn) {
    const int lane = threadIdx.x & 63;
    const int wave = threadIdx.x >> 6;
    const int grow = blockIdx.x * 4 + wave;
    const bool isX = grow < bn;
    const int row  = isX ? grow : grow - bn;
    const float* src = isX ? x : neg;
    unsigned char* dst = isX ? Xn : Nn;

    const float4* s = (const float4*)(src + (size_t)row * DIM);
    float4 xv[4], pv[4];
    float sxx = 0.f, spp = 0.f, sxp = 0.f;
#pragma unroll
    for (int i = 0; i < 4; i++) {
        xv[i] = s[lane + 64 * i];
        sxx += xv[i].x * xv[i].x + xv[i].y * xv[i].y + xv[i].z * xv[i].z + xv[i].w * xv[i].w;
    }
    if (isX) {
        const float4* p = (const float4*)(pos + (size_t)row * DIM);
#pragma unroll
        for (int i = 0; i < 4; i++) {
            pv[i] = p[lane + 64 * i];
            spp += pv[i].x * pv[i].x + pv[i].y * pv[i].y + pv[i].z * pv[i].z + pv[i].w * pv[i].w;
            sxp += xv[i].x * pv[i].x + xv[i].y * pv[i].y + xv[i].z * pv[i].z + xv[i].w * pv[i].w;
        }
#pragma unroll
        for (int off = 1; off < 64; off <<= 1) {
            sxx += __shfl_xor(sxx, off);
            spp += __shfl_xor(spp, off);
            sxp += __shfl_xor(sxp, off);
        }
    } else {
#pragma unroll
        for (int off = 1; off < 64; off <<= 1) sxx += __shfl_xor(sxx, off);
    }
    const float nx  = sqrtf(sxx);
    const float inv = (nx > 0.f) ? (16.f / nx) : 0.f;   // x16 -> e4m3 sweet spot
    if (isX && lane == 0) {
        const float np = sqrtf(spp);
        simOut[row] = sxp / fmaxf(nx * np, EPS);
        rowsum[row] = 0.f;
    }
    unsigned int t;
    t = __builtin_amdgcn_cvt_pk_fp8_f32(xv[0].x * inv, xv[0].y * inv, 0, false);
    unsigned int q0 = __builtin_amdgcn_cvt_pk_fp8_f32(xv[0].z * inv, xv[0].w * inv, t, true);
    t = __builtin_amdgcn_cvt_pk_fp8_f32(xv[1].x * inv, xv[1].y * inv, 0, false);
    unsigned int q1 = __builtin_amdgcn_cvt_pk_fp8_f32(xv[1].z * inv, xv[1].w * inv, t, true);
    t = __builtin_amdgcn_cvt_pk_fp8_f32(xv[2].x * inv, xv[2].y * inv, 0, false);
    unsigned int q2 = __builtin_amdgcn_cvt_pk_fp8_f32(xv[2].z * inv, xv[2].w * inv, t, true);
    t = __builtin_amdgcn_cvt_pk_fp8_f32(xv[3].x * inv, xv[3].y * inv, 0, false);
    unsigned int q3 = __builtin_amdgcn_cvt_pk_fp8_f32(xv[3].z * inv, xv[3].w * inv, t, true);

    unsigned int* wr = (unsigned int*)(dst + (size_t)row * DIM);
    wr[lane]       = q0;
    wr[lane + 64]  = q1;
    wr[lane + 128] = q2;
    wr[lane + 192] = q3;
}

// ---------------------------------------------------------------------------
// Fused MX-fp8 GEMM: rowsum[i] += sum_j exp( unit(x_i) . unit(neg_j) )
// 256x128 tile, 8 waves, per-wave 64x64 (4x4 frags of 16x16), MX cell
// mfma_scale_f32_16x16x128_f8f6f4 (R3-verified). BK=128-B k-window,
// THREE-buffer rotation (144 KB dyn LDS), prefetch distance 2,
// counted s_waitcnt vmcnt(6) at window boundaries ONLY (never 0 in loop).
// Per window, two sub-phases per wave, each {3 glds issue | frag ds_reads |
// setprio(1) 8 MFMA setprio(0)} with a raw s_barrier between — the T3+T4
// interleave that amortizes the stage stall R3's vmcnt(0) drain exposed.
// vmcnt ledger (6 glds/wave/window, in-order): prologue 12 -> wait(6);
// each window issues 6 for w+2, boundary wait(6) => w+1 landed, w+2 in
// flight across the barrier; w=6 waits(0); w=7 computes only.
// Buffer hazard: window w stages buf (w+2)%3 != read buf w%3; first issue
// is after the barrier that retired all reads of that buffer.
// LDS swizzle + fragment layout identical to R3 (verified): slot p of row r
// holds logical chunk p ^ (r&7); lane&15=row, q=lane>>4 owns k-bytes
// [32q,32q+32) via 2 b128 at slot (2q)^(r&7) and ^16.
// ---------------------------------------------------------------------------
__global__ __launch_bounds__(512, 2)
void gemm_exp_rowsum(const unsigned char* __restrict__ Xn,
                     const unsigned char* __restrict__ Nn,
                     float* __restrict__ rowsum) {
    constexpr int KB   = DIM;            // 1024 bytes per fp8 row
    constexpr int BK   = 128;            // bytes per k-window (K=128 elems)
    constexpr int BUFB = 256 * BK + 128 * BK;   // 48 KB: A(32K) then B(16K)
    constexpr int BOFF = 256 * BK;       // B area offset within a buffer
    extern __shared__ unsigned char smem[];     // 3 * BUFB = 144 KB

    const int tid  = threadIdx.x;
    const int lane = tid & 63;
    const int wave = tid >> 6;                 // 0..7

    // T1: bijective chunked XCD swizzle (nwg = 1024, divisible by 8)
    const int nwg  = gridDim.x * gridDim.y;
    const int bid  = blockIdx.y * gridDim.x + blockIdx.x;
    const int swz  = (bid & 7) * (nwg >> 3) + (bid >> 3);
    const int rowBase = (swz / gridDim.x) * 256;
    const int colBase = (swz % gridDim.x) * 128;

    // staging: one glds = 1 KB = 8 rows x 128 B. lane -> (srow=lane>>3, slot=lane&7).
    // global chunk = slot ^ srow (rows 8-aligned per glds => key = srow).
    const int srow = lane >> 3;
    const int sch  = (lane & 7) ^ srow;
    const unsigned char* gA = Xn + (size_t)(rowBase + wave * 32 + srow) * KB + sch * 16;
    const unsigned char* gB = Nn + (size_t)(colBase + wave * 16 + srow) * KB + sch * 16;

    const f32x4 fz = {0.f, 0.f, 0.f, 0.f};
    f32x4 acc[4][4];
#pragma unroll
    for (int mi = 0; mi < 4; mi++)
#pragma unroll
        for (int ni = 0; ni < 4; ni++) acc[mi][ni] = fz;

    const int m0   = (wave >> 1) * 64;   // 0,64,128,192
    const int n0   = (wave & 1) * 64;    // 0,64
    const int mrow = lane & 15;
    const int q    = lane >> 4;          // k-quarter: bytes [32q, 32q+32)
    const int c0   = ((2 * q) ^ (mrow & 7)) << 4;

    int aoff[4], boff[4];
#pragma unroll
    for (int i = 0; i < 4; i++) {
        aoff[i] = (m0 + 16 * i + mrow) * BK + c0;
        boff[i] = BOFF + (n0 + 16 * i + mrow) * BK + c0;
    }

    // stage half h (0/1) of this wave's slice of window stg into buffer buf:
    // A rows wave*32+16h..+16 (2 glds), B rows wave*16+8h..+8 (1 glds)
#define STAGE_HALF(buf, stg, h)                                                \
    do {                                                                       \
        const int kq = (stg) * BK;                                             \
        unsigned char* Lb = smem + (buf) * BUFB;                               \
        async_copy16(gA + (size_t)(16 * (h)) * KB + kq,                        \
                     Lb + (wave * 32 + 16 * (h)) * BK);                        \
        async_copy16(gA + (size_t)(16 * (h) + 8) * KB + kq,                    \
                     Lb + (wave * 32 + 16 * (h) + 8) * BK);                    \
        async_copy16(gB + (size_t)(8 * (h)) * KB + kq,                         \
                     Lb + BOFF + (wave * 16 + 8 * (h)) * BK);                  \
    } while (0)

#define RD(base, off, dst)                                                     \
    do {                                                                       \
        i32x4 lo_ = *(const i32x4*)((base) + (off));                           \
        i32x4 hi_ = *(const i32x4*)((base) + ((off) ^ 16));                    \
        dst = __builtin_shufflevector(lo_, hi_, 0, 1, 2, 3, 4, 5, 6, 7);       \
    } while (0)

    // prologue: windows 0,1 in flight (12 ops); retire window 0, keep 6.
    STAGE_HALF(0, 0, 0);
    STAGE_HALF(0, 0, 1);
    STAGE_HALF(1, 1, 0);
    STAGE_HALF(1, 1, 1);
    asm volatile("s_waitcnt vmcnt(6)\n\ts_barrier" ::: "memory");

#pragma unroll
    for (int w = 0; w < 8; w++) {
        const int b  = w % 3;
        const int nb = (w + 2) % 3;
        const unsigned char* Ab = smem + b * BUFB;
        i32x8 Af[4], Bf[2];
        // ---- sub-phase 0: stage half 0 of w+2 | read A frags + B lo | 8 MFMA
        if (w < 6) STAGE_HALF(nb, w + 2, 0);
#pragma unroll
        for (int i = 0; i < 4; i++) RD(Ab, aoff[i], Af[i]);
#pragma unroll
        for (int i = 0; i < 2; i++) RD(Ab, boff[i], Bf[i]);
        __builtin_amdgcn_s_setprio(1);
#pragma unroll
        for (int mi = 0; mi < 4; mi++)
#pragma unroll
            for (int ni = 0; ni < 2; ni++)
                acc[mi][ni] = __builtin_amdgcn_mfma_scale_f32_16x16x128_f8f6f4(
                    Af[mi], Bf[ni], acc[mi][ni], 0, 0, 0, SCALE8, 0, SCALE8);
        __builtin_amdgcn_s_setprio(0);
        asm volatile("s_barrier" ::: "memory");
        // ---- sub-phase 1: stage half 1 of w+2 | read B hi | 8 MFMA
        if (w < 6) STAGE_HALF(nb, w + 2, 1);
#pragma unroll
        for (int i = 0; i < 2; i++) RD(Ab, boff[2 + i], Bf[i]);
        __builtin_amdgcn_s_setprio(1);
#pragma unroll
        for (int mi = 0; mi < 4; mi++)
#pragma unroll
            for (int ni = 0; ni < 2; ni++)
                acc[mi][2 + ni] = __builtin_amdgcn_mfma_scale_f32_16x16x128_f8f6f4(
                    Af[mi], Bf[ni], acc[mi][2 + ni], 0, 0, 0, SCALE8, 0, SCALE8);
        __builtin_amdgcn_s_setprio(0);
        // ---- window boundary: counted wait (never 0 until the tail)
        if (w < 6) {
            asm volatile("s_waitcnt vmcnt(6)\n\ts_barrier" ::: "memory");
        } else if (w == 6) {
            asm volatile("s_waitcnt vmcnt(0)\n\ts_barrier" ::: "memory");
        }
    }
#undef STAGE_HALF
#undef RD

    // epilogue (R3-verified): 16x16 C/D layout col=lane&15, row=q*4+reg.
    // exp, sum 4 ni blocks, 16-col shuffle reduce, 4 atomics per q-lane.
#pragma unroll
    for (int mi = 0; mi < 4; mi++) {
        float rs0 = 0.f, rs1 = 0.f, rs2 = 0.f, rs3 = 0.f;
#pragma unroll
        for (int ni = 0; ni < 4; ni++) {
            rs0 += __expf(acc[mi][ni].x);
            rs1 += __expf(acc[mi][ni].y);
            rs2 += __expf(acc[mi][ni].z);
            rs3 += __expf(acc[mi][ni].w);
        }
#pragma unroll
        for (int off = 1; off < 16; off <<= 1) {
            rs0 += __shfl_xor(rs0, off);
            rs1 += __shfl_xor(rs1, off);
            rs2 += __shfl_xor(rs2, off);
            rs3 += __shfl_xor(rs3, off);
        }
        if ((lane & 15) == 0) {
            const int r = rowBase + m0 + mi * 16 + q * 4;
            atomicAdd(&rowsum[r + 0], rs0);
            atomicAdd(&rowsum[r + 1], rs1);
            atomicAdd(&rowsum[r + 2], rs2);
            atomicAdd(&rowsum[r + 3], rs3);
        }
    }
}

__global__ __launch_bounds__(1024)
void loss_kernel(const float* __restrict__ rowsum, const float* __restrict__ sim,
                 float* __restrict__ out, int bn) {
    const int tid  = threadIdx.x;
    const int lane = tid & 63;
    const int wave = tid >> 6;
    float acc = 0.f;
    for (int i = tid; i < bn; i += 1024) acc += logf(rowsum[i]) - sim[i];
#pragma unroll
    for (int off = 1; off < 64; off <<= 1) acc += __shfl_xor(acc, off);
    __shared__ float red[16];
    if (lane == 0) red[wave] = acc;
    __syncthreads();
    if (tid == 0) {
        float t = 0.f;
#pragma unroll
        for (int i = 0; i < 16; i++) t += red[i];
        out[0] = t / (float)bn;
    }
}

extern "C" void kernel_launch(void* const* d_in, const int* in_sizes, int n_in,
                              void* d_out, int out_size, void* d_ws, size_t ws_size,
                              hipStream_t stream) {
    const float* x   = (const float*)d_in[0];
    const float* pos = (const float*)d_in[1];
    const float* neg = (const float*)d_in[2];
    const int bn = in_sizes[0] / DIM;  // 4096
    const int cn = in_sizes[2] / DIM;  // 8192

    // ws layout: Xn fp8 [bn*DIM] | Nn fp8 [cn*DIM] | sim f32 [bn] | rowsum f32 [bn]
    unsigned char* Xn = (unsigned char*)d_ws;
    unsigned char* Nn = Xn + (size_t)bn * DIM;
    float* sim    = (float*)(Nn + (size_t)cn * DIM);
    float* rowsum = sim + bn;

    // opt in to 144 KB dynamic LDS (gfx950: 160 KB/CU). Host-side attribute
    // set, not a stream op — graph-safe.
    static bool attr_done = false;
    if (!attr_done) {
        (void)hipFuncSetAttribute((const void*)gemm_exp_rowsum,
                                  hipFuncAttributeMaxDynamicSharedMemorySize,
                                  147456);
        attr_done = true;
    }

    prep_all<<<dim3((bn + cn) / 4), dim3(256), 0, stream>>>(x, pos, neg, Xn, Nn, sim, rowsum, bn);
    gemm_exp_rowsum<<<dim3(cn / 128, bn / 256), dim3(512), 147456, stream>>>(Xn, Nn, rowsum);
    loss_kernel<<<dim3(1), dim3(1024), 0, stream>>>(rowsum, sim, (float*)d_out, bn);
}